// Round 4
// baseline (242.219 us; speedup 1.0000x reference)
//
#include <hip/hip_runtime.h>
#include <stdint.h>

// out[b,j] = bias[j] + sum_i [ mask*scale_base[i,j]*silu(x[b,i])
//            + mask*scale_fft[i,j]* sum_k ( cos(k*x)*fc0[j,i,k] + sin(k*x)*fc1[j,i,k] ) ]
// R4: materialize A (features, bf16, padded K=16896) + B (weights, same K-layout),
//     then clean HBM-bound MFMA GEMM (128x128 tile, BK=64, KSPLIT=8, XOR-swizzled
//     LDS, dbuf, 1 barrier/iter) + reduce. Fallbacks: R3 path, then atomic path.

#define I_DIM 256
#define O_DIM 256
#define G_DIM 32
#define B_DIM 4096

#define KPAD  16896             // 256*64 fourier + 256 silu + 256 pad
#define KCH   2112              // KPAD / 8 (per-kc chunk)
#define ITERS 33                // KCH / 64

// R3 fallback constants
#define BM 128
#define BN 128
#define ICH 16
#define PITCH 72

typedef short s8v __attribute__((ext_vector_type(8)));
typedef float f4v __attribute__((ext_vector_type(4)));

__device__ __forceinline__ uint32_t pack2bf16(float a, float b) {
  uint32_t ua = __builtin_bit_cast(uint32_t, a);
  uint32_t ub = __builtin_bit_cast(uint32_t, b);
  ua += 0x7FFFu + ((ua >> 16) & 1u);
  ub += 0x7FFFu + ((ub >> 16) & 1u);
  return (ua >> 16) | (ub & 0xFFFF0000u);
}
__device__ __forceinline__ short pack1bf16(float a) {
  return (short)(pack2bf16(a, 0.f) & 0xFFFFu);
}
__device__ __forceinline__ float silu_f(float v) { return v / (1.0f + __expf(-v)); }

// ---------------------------------------------------------------- R4 feat: A
__global__ __launch_bounds__(256) void feat_kernel(
    const float* __restrict__ x, short* __restrict__ Af)
{
  const int b = blockIdx.x, i = threadIdx.x;
  const float xv = x[(size_t)b * I_DIM + i];
  float s1, c1;
  __sincosf(xv, &s1, &c1);
  const float m2 = 2.f * c1;
  uint32_t cb[16], sb[16];
  float c0 = c1, cc = m2 * c1 - 1.f;      // cos k=1,2
  float s0 = s1, ss = m2 * s1;            // sin k=1,2
  cb[0] = pack2bf16(c0, cc);
  sb[0] = pack2bf16(s0, ss);
  #pragma unroll
  for (int p = 1; p < 16; ++p) {
    float c2 = m2 * cc - c0, c3 = m2 * c2 - cc;
    float s2 = m2 * ss - s0, s3 = m2 * s2 - ss;
    cb[p] = pack2bf16(c2, c3); c0 = c2; cc = c3;
    sb[p] = pack2bf16(s2, s3); s0 = s2; ss = s3;
  }
  short* dst = Af + (size_t)b * KPAD + i * 64;
  #pragma unroll
  for (int q = 0; q < 4; ++q)
    ((uint4*)dst)[q] = make_uint4(cb[4*q], cb[4*q+1], cb[4*q+2], cb[4*q+3]);
  #pragma unroll
  for (int q = 0; q < 4; ++q)
    ((uint4*)dst)[4 + q] = make_uint4(sb[4*q], sb[4*q+1], sb[4*q+2], sb[4*q+3]);
  Af[(size_t)b * KPAD + 16384 + i] = pack1bf16(silu_f(xv));
  Af[(size_t)b * KPAD + 16640 + i] = 0;
}

// ---------------------------------------------------------------- R4 prep: B
__global__ __launch_bounds__(256) void prep_b2_kernel(
    const float* __restrict__ fc, const float* __restrict__ mask,
    const float* __restrict__ sfft, const float* __restrict__ sbase,
    short* __restrict__ Bp)
{
  const int gid = blockIdx.x * 256 + threadIdx.x;  // 0..131071
  const int p = gid >> 1, d = gid & 1;
  const int j = p >> 8, i = p & 255;
  const size_t ij = (size_t)i * O_DIM + j;
  const float mk = mask[ij];
  const float sf = sfft[ij] * mk;
  const float* src = fc + (((size_t)d * O_DIM + j) * I_DIM + i) * G_DIM;
  uint32_t wb[16];
  #pragma unroll
  for (int q = 0; q < 8; ++q) {
    float4 v = ((const float4*)src)[q];
    wb[2*q]   = pack2bf16(v.x * sf, v.y * sf);
    wb[2*q+1] = pack2bf16(v.z * sf, v.w * sf);
  }
  uint4* dst = (uint4*)(Bp + (size_t)j * KPAD + i * 64 + d * 32);
  dst[0] = make_uint4(wb[0],  wb[1],  wb[2],  wb[3]);
  dst[1] = make_uint4(wb[4],  wb[5],  wb[6],  wb[7]);
  dst[2] = make_uint4(wb[8],  wb[9],  wb[10], wb[11]);
  dst[3] = make_uint4(wb[12], wb[13], wb[14], wb[15]);
  if (d) Bp[(size_t)j * KPAD + 16384 + i] = pack1bf16(sbase[ij] * mk);
  else   Bp[(size_t)j * KPAD + 16640 + i] = 0;
}

// ---------------------------------------------------------------- R4 GEMM
// 128x128 tile, BK=64, dbuf LDS w/ XOR swizzle, 1 barrier/iter.
__global__ __launch_bounds__(256, 2) void gemm_kernel(
    const short* __restrict__ Af, const short* __restrict__ Bp,
    float* __restrict__ partial)          // (8, 4096, 256)
{
  __shared__ short SH[2][2][128 * 64];    // [buf][A/B][row*64 + slot*8]  64 KB

  const int tid = threadIdx.x;
  const int bx  = blockIdx.x;
  const int kc  = bx & 7;                 // XCD affinity: B-slice L2-resident
  const int bn  = (bx >> 3) & 1;          // bn-pair 8 apart -> same XCD, A shared
  const int bm  = bx >> 4;

  const int lane = tid & 63;
  const int wave = tid >> 6;
  const int wm   = wave & 1;
  const int wn   = wave >> 1;
  const int l15  = lane & 15;
  const int quad = lane >> 4;

  // staging: thread -> (row r = wave*32 + q*8 + (lane>>3), chunk c = lane&7)
  const int srow  = (lane >> 3);          // 0..7
  const int schk  = lane & 7;
  const int r0    = wave * 32 + srow;
  // LDS slot for row r, global chunk c: slot = c ^ (r&7);  r&7 == srow
  const int wofs  = r0 * 64 + (schk ^ srow) * 8;   // shorts, +q*8*64 per q

  const short* aptr = Af + (size_t)(bm * 128 + r0) * KPAD + kc * KCH + schk * 8;
  const short* bptr = Bp + (size_t)(bn * 128 + r0) * KPAD + kc * KCH + schk * 8;

  f4v acc[4][4];
  #pragma unroll
  for (int a = 0; a < 4; ++a)
    #pragma unroll
    for (int b = 0; b < 4; ++b)
      acc[a][b] = (f4v){0.f, 0.f, 0.f, 0.f};

  // prefetch it=0
  uint4 ra[4], rb[4];
  #pragma unroll
  for (int q = 0; q < 4; ++q) {
    ra[q] = *(const uint4*)(aptr + (size_t)q * 8 * KPAD);
    rb[q] = *(const uint4*)(bptr + (size_t)q * 8 * KPAD);
  }

  int pb = 0;
  for (int it = 0; it < ITERS; ++it) {
    // store prefetched regs into buf pb (swizzled)
    #pragma unroll
    for (int q = 0; q < 4; ++q) {
      *(uint4*)&SH[pb][0][wofs + q * 8 * 64] = ra[q];
      *(uint4*)&SH[pb][1][wofs + q * 8 * 64] = rb[q];
    }
    // prefetch it+1
    if (it + 1 < ITERS) {
      const size_t ko = (size_t)(it + 1) * 64;
      #pragma unroll
      for (int q = 0; q < 4; ++q) {
        ra[q] = *(const uint4*)(aptr + ko + (size_t)q * 8 * KPAD);
        rb[q] = *(const uint4*)(bptr + ko + (size_t)q * 8 * KPAD);
      }
    }
    __syncthreads();
    // MFMA on buf pb
    #pragma unroll
    for (int ks = 0; ks < 2; ++ks) {
      s8v a[4], b[4];
      #pragma unroll
      for (int tm = 0; tm < 4; ++tm) {
        const int r = wm * 64 + tm * 16 + l15;
        a[tm] = *(const s8v*)&SH[pb][0][r * 64 + (((ks * 4 + quad) ^ (l15 & 7)) * 8)];
      }
      #pragma unroll
      for (int tn = 0; tn < 4; ++tn) {
        const int r = wn * 64 + tn * 16 + l15;
        b[tn] = *(const s8v*)&SH[pb][1][r * 64 + (((ks * 4 + quad) ^ (l15 & 7)) * 8)];
      }
      #pragma unroll
      for (int tm = 0; tm < 4; ++tm)
        #pragma unroll
        for (int tn = 0; tn < 4; ++tn)
          acc[tm][tn] = __builtin_amdgcn_mfma_f32_16x16x32_bf16(a[tm], b[tn], acc[tm][tn], 0, 0, 0);
    }
    pb ^= 1;
  }

  float* pbase = partial + (size_t)kc * B_DIM * O_DIM;
  #pragma unroll
  for (int tm = 0; tm < 4; ++tm) {
    #pragma unroll
    for (int tn = 0; tn < 4; ++tn) {
      const int n_g = bn * 128 + wn * 64 + tn * 16 + l15;
      f4v v = acc[tm][tn];
      #pragma unroll
      for (int r = 0; r < 4; ++r) {
        const int m_g = bm * 128 + wm * 64 + tm * 16 + quad * 4 + r;
        pbase[(size_t)m_g * O_DIM + n_g] = v[r];
      }
    }
  }
}

// ---------------------------------------------------------------- reduce (nk runtime)
__global__ __launch_bounds__(256) void reduce_kernel(
    const float* __restrict__ partial, const float* __restrict__ bias,
    float* __restrict__ out, int nk)
{
  const int g  = blockIdx.x * 256 + threadIdx.x;
  const int m  = g >> 6;
  const int n4 = (g & 63) << 2;
  float4 acc = ((const float4*)(bias + n4))[0];
  for (int kc = 0; kc < nk; ++kc) {
    float4 v = ((const float4*)(partial + ((size_t)kc * B_DIM + m) * O_DIM + n4))[0];
    acc.x += v.x; acc.y += v.y; acc.z += v.z; acc.w += v.w;
  }
  ((float4*)(out + (size_t)m * O_DIM + n4))[0] = acc;
}

// ================================================================ R3 fallback
__global__ __launch_bounds__(256) void prep_b_kernel(
    const float* __restrict__ fc, const float* __restrict__ mask,
    const float* __restrict__ sfft, short* __restrict__ Bp)
{
  const int gid = blockIdx.x * 256 + threadIdx.x;
  const int p = gid >> 1, d = gid & 1;
  const int j = p >> 8, i = p & 255;
  const float sf = sfft[i * O_DIM + j] * mask[i * O_DIM + j];
  const float* src = fc + (((size_t)d * O_DIM + j) * I_DIM + i) * G_DIM;
  uint32_t wb[16];
  #pragma unroll
  for (int q = 0; q < 8; ++q) {
    float4 v = ((const float4*)src)[q];
    wb[2*q]   = pack2bf16(v.x * sf, v.y * sf);
    wb[2*q+1] = pack2bf16(v.z * sf, v.w * sf);
  }
  uint4* dst = (uint4*)(Bp + (size_t)p * 64 + d * 32);
  dst[0] = make_uint4(wb[0],  wb[1],  wb[2],  wb[3]);
  dst[1] = make_uint4(wb[4],  wb[5],  wb[6],  wb[7]);
  dst[2] = make_uint4(wb[8],  wb[9],  wb[10], wb[11]);
  dst[3] = make_uint4(wb[12], wb[13], wb[14], wb[15]);
}

__global__ __launch_bounds__(256, 4) void kan_main(
    const float* __restrict__ x, const short* __restrict__ Bp,
    const float* __restrict__ mask, const float* __restrict__ scale_base,
    float* __restrict__ partial)
{
  __shared__ short A_lds[BM * PITCH];
  __shared__ short B_lds[BN * PITCH];

  const int tid = threadIdx.x;
  const int bx  = blockIdx.x;
  const int kc  = bx & 15;
  const int bn  = (bx >> 4) & 1;
  const int bm  = bx >> 5;
  const int i0  = kc * ICH;

  const int lane = tid & 63;
  const int wave = tid >> 6;
  const int wm   = wave & 1;
  const int wn   = wave >> 1;
  const int l15  = lane & 15;
  const int kgrp = (lane >> 4) * 8;

  f4v acc[4][4];
  #pragma unroll
  for (int a = 0; a < 4; ++a)
    #pragma unroll
    for (int b = 0; b < 4; ++b)
      acc[a][b] = (f4v){0.f, 0.f, 0.f, 0.f};

  const int row  = tid >> 1;
  const int half = tid & 1;
  const int mg   = bm * BM + row;
  const int jg   = bn * BN + row;

  const float* xrow = x + (size_t)mg * I_DIM + i0;
  const short* bsrc = Bp + ((size_t)jg * I_DIM + i0) * 64 + half * 32;
  uint32_t* Arow = (uint32_t*)&A_lds[row * PITCH + half * 32];
  uint4*    Brow = (uint4*)&B_lds[row * PITCH + half * 32];

  uint4 bpre[4];
  #pragma unroll
  for (int q = 0; q < 4; ++q) bpre[q] = ((const uint4*)bsrc)[q];

  for (int it = 0; it < ICH; ++it) {
    __syncthreads();
    Brow[0] = bpre[0]; Brow[1] = bpre[1]; Brow[2] = bpre[2]; Brow[3] = bpre[3];
    if (it + 1 < ICH) {
      const uint4* nb = (const uint4*)(bsrc + (size_t)(it + 1) * 64);
      #pragma unroll
      for (int q = 0; q < 4; ++q) bpre[q] = nb[q];
    }
    {
      const float xv = xrow[it];
      float s, c;
      __sincosf(xv, &s, &c);
      const float m2 = 2.f * c;
      float f0 = half ? s : c;
      float f1 = m2 * f0 - (half ? 0.f : 1.f);
      uint32_t fb[16];
      fb[0] = pack2bf16(f0, f1);
      #pragma unroll
      for (int p = 1; p < 16; ++p) {
        float f2 = m2 * f1 - f0;
        float f3 = m2 * f2 - f1;
        fb[p] = pack2bf16(f2, f3);
        f0 = f2; f1 = f3;
      }
      ((uint4*)Arow)[0] = make_uint4(fb[0],  fb[1],  fb[2],  fb[3]);
      ((uint4*)Arow)[1] = make_uint4(fb[4],  fb[5],  fb[6],  fb[7]);
      ((uint4*)Arow)[2] = make_uint4(fb[8],  fb[9],  fb[10], fb[11]);
      ((uint4*)Arow)[3] = make_uint4(fb[12], fb[13], fb[14], fb[15]);
    }
    __syncthreads();
    #pragma unroll
    for (int ks = 0; ks < 2; ++ks) {
      s8v a[4], b[4];
      #pragma unroll
      for (int tm = 0; tm < 4; ++tm)
        a[tm] = *(const s8v*)&A_lds[(wm * 64 + tm * 16 + l15) * PITCH + ks * 32 + kgrp];
      #pragma unroll
      for (int tn = 0; tn < 4; ++tn)
        b[tn] = *(const s8v*)&B_lds[(wn * 64 + tn * 16 + l15) * PITCH + ks * 32 + kgrp];
      #pragma unroll
      for (int tm = 0; tm < 4; ++tm)
        #pragma unroll
        for (int tn = 0; tn < 4; ++tn)
          acc[tm][tn] = __builtin_amdgcn_mfma_f32_16x16x32_bf16(a[tm], b[tn], acc[tm][tn], 0, 0, 0);
    }
  }

  __syncthreads();
  {
    const float* xb = xrow + half * 8;
    float4 v0 = ((const float4*)xb)[0];
    float4 v1 = ((const float4*)xb)[1];
    uint32_t a0 = pack2bf16(silu_f(v0.x), silu_f(v0.y));
    uint32_t a1 = pack2bf16(silu_f(v0.z), silu_f(v0.w));
    uint32_t a2 = pack2bf16(silu_f(v1.x), silu_f(v1.y));
    uint32_t a3 = pack2bf16(silu_f(v1.z), silu_f(v1.w));
    ((uint4*)&A_lds[row * PITCH + half * 8])[0]      = make_uint4(a0, a1, a2, a3);
    ((uint4*)&A_lds[row * PITCH + 16 + half * 8])[0] = make_uint4(0, 0, 0, 0);
    uint32_t w[4];
    #pragma unroll
    for (int p = 0; p < 4; ++p) {
      const int ia = i0 + half * 8 + 2 * p;
      const size_t o0 = (size_t)ia * O_DIM + jg;
      const size_t o1 = o0 + O_DIM;
      w[p] = pack2bf16(scale_base[o0] * mask[o0], scale_base[o1] * mask[o1]);
    }
    ((uint4*)&B_lds[row * PITCH + half * 8])[0]      = make_uint4(w[0], w[1], w[2], w[3]);
    ((uint4*)&B_lds[row * PITCH + 16 + half * 8])[0] = make_uint4(0, 0, 0, 0);
  }
  __syncthreads();
  {
    s8v a[4], b[4];
    #pragma unroll
    for (int tm = 0; tm < 4; ++tm)
      a[tm] = *(const s8v*)&A_lds[(wm * 64 + tm * 16 + l15) * PITCH + kgrp];
    #pragma unroll
    for (int tn = 0; tn < 4; ++tn)
      b[tn] = *(const s8v*)&B_lds[(wn * 64 + tn * 16 + l15) * PITCH + kgrp];
    #pragma unroll
    for (int tm = 0; tm < 4; ++tm)
      #pragma unroll
      for (int tn = 0; tn < 4; ++tn)
        acc[tm][tn] = __builtin_amdgcn_mfma_f32_16x16x32_bf16(a[tm], b[tn], acc[tm][tn], 0, 0, 0);
  }

  float* pbase = partial + (size_t)kc * B_DIM * O_DIM;
  const int quad = lane >> 4;
  #pragma unroll
  for (int tm = 0; tm < 4; ++tm) {
    #pragma unroll
    for (int tn = 0; tn < 4; ++tn) {
      const int n_g = bn * BN + wn * 64 + tn * 16 + l15;
      f4v v = acc[tm][tn];
      #pragma unroll
      for (int r = 0; r < 4; ++r) {
        const int m_g = bm * BM + wm * 64 + tm * 16 + quad * 4 + r;
        pbase[(size_t)m_g * O_DIM + n_g] = v[r];
      }
    }
  }
}

extern "C" void kernel_launch(void* const* d_in, const int* in_sizes, int n_in,
                              void* d_out, int out_size, void* d_ws, size_t ws_size,
                              hipStream_t stream) {
  const float* x          = (const float*)d_in[0];
  const float* fc         = (const float*)d_in[1];
  const float* bias       = (const float*)d_in[2];
  const float* mask       = (const float*)d_in[3];
  const float* scale_base = (const float*)d_in[4];
  const float* scale_fft  = (const float*)d_in[5];
  float* out = (float*)d_out;

  const size_t AF_B    = (size_t)B_DIM * KPAD * 2;          // 138,412,032
  const size_t BP2_B   = (size_t)O_DIM * KPAD * 2;          //   8,650,752
  const size_t PART8_B = (size_t)8 * B_DIM * O_DIM * 4;     //  33,554,432
  const size_t BP3_B   = (size_t)O_DIM * I_DIM * 64 * 2;    //   8,388,608
  const size_t PART16_B= (size_t)16 * B_DIM * O_DIM * 4;    //  67,108,864

  if (ws_size >= AF_B + BP2_B + PART8_B) {
    short* Af      = (short*)d_ws;
    short* Bp      = (short*)((char*)d_ws + AF_B);
    float* partial = (float*)((char*)d_ws + AF_B + BP2_B);
    feat_kernel<<<dim3(4096), dim3(256), 0, stream>>>(x, Af);
    prep_b2_kernel<<<dim3(512), dim3(256), 0, stream>>>(fc, mask, scale_fft, scale_base, Bp);
    gemm_kernel<<<dim3(512), dim3(256), 0, stream>>>(Af, Bp, partial);
    reduce_kernel<<<dim3(1024), dim3(256), 0, stream>>>(partial, bias, out, 8);
  } else if (ws_size >= BP3_B + PART16_B) {
    short* Bp      = (short*)d_ws;
    float* partial = (float*)((char*)d_ws + BP3_B);
    prep_b_kernel<<<dim3(512), dim3(256), 0, stream>>>(fc, mask, scale_fft, Bp);
    kan_main<<<dim3(1024), dim3(256), 0, stream>>>(x, Bp, mask, scale_base, partial);
    reduce_kernel<<<dim3(1024), dim3(256), 0, stream>>>(partial, bias, out, 16);
  }
}

// Round 6
// 142.919 us; speedup vs baseline: 1.6948x; 1.6948x over previous
//
#include <hip/hip_runtime.h>
#include <stdint.h>

// out[b,j] = bias[j] + sum_i [ mask*scale_base[i,j]*silu(x[b,i])
//            + mask*scale_fft[i,j]* sum_k ( cos(kx)fc0[j,i,k] + sin(kx)fc1[j,i,k] ) ]
// R6: R5 scheme with the DMA stride bug fixed (q*8*64, not q*16*64):
//  (1) B staged via global_load_lds from a pre-XOR-swizzled i-major pack,
//  (2) A-gen for it+1 software-pipelined into the MFMA(it) phase,
//  (3) KSPLIT=16, 4 blk/CU, partial+reduce (ws 75.5 MB).

#define I_DIM 256
#define O_DIM 256
#define G_DIM 32
#define B_DIM 4096

#define BM 128
#define BN 128
#define KSPLIT 16
#define ICH 16                  // i's per K-chunk
#define PITCH 72                // A_lds row pitch in shorts (padded; ds_write path)

typedef short s8v __attribute__((ext_vector_type(8)));
typedef float f4v __attribute__((ext_vector_type(4)));

__device__ __forceinline__ uint32_t pack2bf16(float a, float b) {
  uint32_t ua = __builtin_bit_cast(uint32_t, a);
  uint32_t ub = __builtin_bit_cast(uint32_t, b);
  ua += 0x7FFFu + ((ua >> 16) & 1u);     // RNE
  ub += 0x7FFFu + ((ub >> 16) & 1u);
  return (ua >> 16) | (ub & 0xFFFF0000u);
}
__device__ __forceinline__ float silu_f(float v) { return v / (1.0f + __expf(-v)); }

// cos/sin Chebyshev features k=1..32 for one (row, half): 16 packed uint32
__device__ __forceinline__ void gen_feat(float xv, int half, uint32_t* fb) {
  float s, c;
  __sincosf(xv, &s, &c);
  const float m2 = 2.f * c;
  float f0 = half ? s : c;                       // k=1
  float f1 = m2 * f0 - (half ? 0.f : 1.f);       // k=2
  fb[0] = pack2bf16(f0, f1);
  #pragma unroll
  for (int p = 1; p < 16; ++p) {
    float f2 = m2 * f1 - f0;
    float f3 = m2 * f2 - f1;
    fb[p] = pack2bf16(f2, f3);
    f0 = f2; f1 = f3;
  }
}

// ------------------------------------------------ prep: pack B, i-major, XOR-swizzled
// Bp[(i*256+j)*64 + s*8 ..] = chunk (s ^ (j&7)) of W[j,i,0:64]
// where W cols 0..31 = fc0[j,i,:]*sf, cols 32..63 = fc1[j,i,:]*sf
__global__ __launch_bounds__(256) void prep_bs_kernel(
    const float* __restrict__ fc, const float* __restrict__ mask,
    const float* __restrict__ sfft, short* __restrict__ Bp)
{
  const int gid = blockIdx.x * 256 + threadIdx.x;   // 65536 threads
  const int i = gid >> 8, j = gid & 255;
  const size_t ij = (size_t)i * O_DIM + j;
  const float sf = sfft[ij] * mask[ij];
  const float* f0 = fc + ((size_t)j * I_DIM + i) * G_DIM;
  const float* f1 = f0 + (size_t)O_DIM * I_DIM * G_DIM;
  uint32_t w[32];
  #pragma unroll
  for (int q = 0; q < 8; ++q) {
    float4 v = ((const float4*)f0)[q];
    w[2*q]   = pack2bf16(v.x * sf, v.y * sf);
    w[2*q+1] = pack2bf16(v.z * sf, v.w * sf);
  }
  #pragma unroll
  for (int q = 0; q < 8; ++q) {
    float4 v = ((const float4*)f1)[q];
    w[16+2*q]   = pack2bf16(v.x * sf, v.y * sf);
    w[16+2*q+1] = pack2bf16(v.z * sf, v.w * sf);
  }
  uint4 ch[8];
  #pragma unroll
  for (int c = 0; c < 8; ++c)
    ch[c] = make_uint4(w[4*c], w[4*c+1], w[4*c+2], w[4*c+3]);
  uint4* dst = (uint4*)(Bp + (size_t)(i * 256 + j) * 64);
  const int xr = j & 7;
  #pragma unroll
  for (int s = 0; s < 8; ++s) dst[s] = ch[s ^ xr];
}

// ------------------------------------------------ main GEMM
__global__ __launch_bounds__(256, 4) void kan_main2(
    const float* __restrict__ x,
    const short* __restrict__ Bp,
    const float* __restrict__ mask,
    const float* __restrict__ scale_base,
    float* __restrict__ partial)          // (16, 4096, 256)
{
  __shared__ short A_lds[BM * PITCH];     // padded, ds_write path
  __shared__ short B_lds[BN * 64];        // unpadded, DMA image (pre-swizzled)

  const int tid = threadIdx.x;
  const int bx  = blockIdx.x;
  const int kc  = bx & 15;                // XCD affinity: Bp slice L2-resident
  const int bn  = (bx >> 4) & 1;
  const int bm  = bx >> 5;
  const int i0  = kc * ICH;

  const int lane = tid & 63;
  const int wave = tid >> 6;
  const int wm   = wave & 1;
  const int wn   = wave >> 1;
  const int l15  = lane & 15;
  const int quad = lane >> 4;
  const int kgrp = quad * 8;

  f4v acc[4][4];
  #pragma unroll
  for (int a = 0; a < 4; ++a)
    #pragma unroll
    for (int b = 0; b < 4; ++b)
      acc[a][b] = (f4v){0.f, 0.f, 0.f, 0.f};

  const int row  = tid >> 1;
  const int half = tid & 1;
  const int mg   = bm * BM + row;
  const int jg   = bn * BN + row;

  const float* xrow = x + (size_t)mg * I_DIM + i0;
  uint32_t* Arow = (uint32_t*)&A_lds[row * PITCH + half * 32];
  const int q0 = wave * 4;                // 4 DMA insts per wave

  uint32_t aNext[16];
  gen_feat(xrow[0], half, aNext);

  for (int it = 0; it < ICH; ++it) {
    __syncthreads();                      // readers of it-1 done

    // A: store regs generated during previous MFMA phase
    ((uint4*)Arow)[0] = make_uint4(aNext[0],  aNext[1],  aNext[2],  aNext[3]);
    ((uint4*)Arow)[1] = make_uint4(aNext[4],  aNext[5],  aNext[6],  aNext[7]);
    ((uint4*)Arow)[2] = make_uint4(aNext[8],  aNext[9],  aNext[10], aNext[11]);
    ((uint4*)Arow)[3] = make_uint4(aNext[12], aNext[13], aNext[14], aNext[15]);

    // B: direct HBM/L2 -> LDS DMA. One inst = 64 lanes x 16B = 1KB = 8 rows.
    // 16 insts (4/wave) tile BN=128 rows; stride q*8*64 shorts = q*1KB.
    {
      const size_t rbase = ((size_t)(i0 + it) * 256 + bn * BN) * 64;
      #pragma unroll
      for (int c = 0; c < 4; ++c) {
        const int q = q0 + c;
        const short* g = Bp + rbase + (size_t)q * 8 * 64 + lane * 8;
        __builtin_amdgcn_global_load_lds(
            (const __attribute__((address_space(1))) void*)g,
            (__attribute__((address_space(3))) void*)&B_lds[q * 8 * 64],
            16, 0, 0);
      }
    }

    __syncthreads();                      // drains vmcnt (DMA) + lgkm (A writes)

    if (it + 1 < ICH) gen_feat(xrow[it + 1], half, aNext);  // overlaps MFMA below

    #pragma unroll
    for (int ks = 0; ks < 2; ++ks) {
      s8v a[4], b[4];
      #pragma unroll
      for (int tm = 0; tm < 4; ++tm)
        a[tm] = *(const s8v*)&A_lds[(wm * 64 + tm * 16 + l15) * PITCH + ks * 32 + kgrp];
      #pragma unroll
      for (int tn = 0; tn < 4; ++tn) {
        const int r = wn * 64 + tn * 16 + l15;
        b[tn] = *(const s8v*)&B_lds[r * 64 + ((ks * 4 + quad) ^ (r & 7)) * 8];
      }
      #pragma unroll
      for (int tm = 0; tm < 4; ++tm)
        #pragma unroll
        for (int tn = 0; tn < 4; ++tn)
          acc[tm][tn] = __builtin_amdgcn_mfma_f32_16x16x32_bf16(a[tm], b[tn], acc[tm][tn], 0, 0, 0);
    }
  }

  // ---------------- base tile: K=32 (16 silu features + 16 zeros)
  __syncthreads();
  {
    const float* xb = xrow + half * 8;
    float4 v0 = ((const float4*)xb)[0];
    float4 v1 = ((const float4*)xb)[1];
    uint32_t a0 = pack2bf16(silu_f(v0.x), silu_f(v0.y));
    uint32_t a1 = pack2bf16(silu_f(v0.z), silu_f(v0.w));
    uint32_t a2 = pack2bf16(silu_f(v1.x), silu_f(v1.y));
    uint32_t a3 = pack2bf16(silu_f(v1.z), silu_f(v1.w));
    ((uint4*)&A_lds[row * PITCH + half * 8])[0]      = make_uint4(a0, a1, a2, a3);
    ((uint4*)&A_lds[row * PITCH + 16 + half * 8])[0] = make_uint4(0, 0, 0, 0);

    uint32_t w[4];
    #pragma unroll
    for (int p = 0; p < 4; ++p) {
      const int ia = i0 + half * 8 + 2 * p;
      const size_t o0 = (size_t)ia * O_DIM + jg;
      const size_t o1 = o0 + O_DIM;
      w[p] = pack2bf16(scale_base[o0] * mask[o0], scale_base[o1] * mask[o1]);
    }
    const int xr = row & 7;
    ((uint4*)&B_lds[row * 64])[half ^ xr]       = make_uint4(w[0], w[1], w[2], w[3]);
    ((uint4*)&B_lds[row * 64])[(2 + half) ^ xr] = make_uint4(0, 0, 0, 0);
  }
  __syncthreads();
  {
    s8v a[4], b[4];
    #pragma unroll
    for (int tm = 0; tm < 4; ++tm)
      a[tm] = *(const s8v*)&A_lds[(wm * 64 + tm * 16 + l15) * PITCH + kgrp];
    #pragma unroll
    for (int tn = 0; tn < 4; ++tn) {
      const int r = wn * 64 + tn * 16 + l15;
      b[tn] = *(const s8v*)&B_lds[r * 64 + (quad ^ (r & 7)) * 8];
    }
    #pragma unroll
    for (int tm = 0; tm < 4; ++tm)
      #pragma unroll
      for (int tn = 0; tn < 4; ++tn)
        acc[tm][tn] = __builtin_amdgcn_mfma_f32_16x16x32_bf16(a[tm], b[tn], acc[tm][tn], 0, 0, 0);
  }

  // ---------------- epilogue: coalesced partial stores
  float* pbase = partial + (size_t)kc * B_DIM * O_DIM;
  #pragma unroll
  for (int tm = 0; tm < 4; ++tm) {
    #pragma unroll
    for (int tn = 0; tn < 4; ++tn) {
      const int n_g = bn * BN + wn * 64 + tn * 16 + l15;
      f4v v = acc[tm][tn];
      #pragma unroll
      for (int r = 0; r < 4; ++r) {
        const int m_g = bm * BM + wm * 64 + tm * 16 + quad * 4 + r;
        pbase[(size_t)m_g * O_DIM + n_g] = v[r];
      }
    }
  }
}

// ------------------------------------------------ reduce
__global__ __launch_bounds__(256) void reduce_kernel(
    const float* __restrict__ partial, const float* __restrict__ bias,
    float* __restrict__ out, int nk)
{
  const int g  = blockIdx.x * 256 + threadIdx.x;
  const int m  = g >> 6;
  const int n4 = (g & 63) << 2;
  float4 acc = ((const float4*)(bias + n4))[0];
  for (int kc = 0; kc < nk; ++kc) {
    float4 v = ((const float4*)(partial + ((size_t)kc * B_DIM + m) * O_DIM + n4))[0];
    acc.x += v.x; acc.y += v.y; acc.z += v.z; acc.w += v.w;
  }
  ((float4*)(out + (size_t)m * O_DIM + n4))[0] = acc;
}

// ================================================ ws-free atomic fallback (R2)
__global__ __launch_bounds__(256, 4) void kan_fft_fallback(
    const float* __restrict__ x, const float* __restrict__ fc,
    const float* __restrict__ bias, const float* __restrict__ mask,
    const float* __restrict__ scale_base, const float* __restrict__ scale_fft,
    float* __restrict__ out)
{
  __shared__ short A_lds[BM * PITCH];
  __shared__ short B_lds[BN * PITCH];

  const int tid = threadIdx.x;
  const int bx  = blockIdx.x;
  const int kc  = bx & 15;
  const int bn  = (bx >> 4) & 1;
  const int bm  = bx >> 5;
  const int i0  = kc * ICH;

  const int lane = tid & 63;
  const int wave = tid >> 6;
  const int wm   = wave & 1;
  const int wn   = wave >> 1;
  const int l15  = lane & 15;
  const int kgrp = (lane >> 4) * 8;

  f4v acc[4][4];
  #pragma unroll
  for (int a = 0; a < 4; ++a)
    #pragma unroll
    for (int b = 0; b < 4; ++b)
      acc[a][b] = (f4v){0.f, 0.f, 0.f, 0.f};

  const int row  = tid >> 1;
  const int half = tid & 1;
  const int mg   = bm * BM + row;
  const int jg   = bn * BN + row;

  const float* xrow   = x + (size_t)mg * I_DIM + i0;
  const float* fcbase = fc + (size_t)half * (O_DIM * I_DIM * G_DIM)
                           + ((size_t)jg * I_DIM + i0) * G_DIM;
  uint32_t* Arow = (uint32_t*)&A_lds[row * PITCH + half * 32];
  uint32_t* Brow = (uint32_t*)&B_lds[row * PITCH + half * 32];

  for (int it = 0; it < ICH; ++it) {
    __syncthreads();
    {
      uint32_t fb[16];
      gen_feat(xrow[it], half, fb);
      ((uint4*)Arow)[0] = make_uint4(fb[0],  fb[1],  fb[2],  fb[3]);
      ((uint4*)Arow)[1] = make_uint4(fb[4],  fb[5],  fb[6],  fb[7]);
      ((uint4*)Arow)[2] = make_uint4(fb[8],  fb[9],  fb[10], fb[11]);
      ((uint4*)Arow)[3] = make_uint4(fb[12], fb[13], fb[14], fb[15]);
    }
    {
      const int i = i0 + it;
      const size_t ij = (size_t)i * O_DIM + jg;
      const float sf  = scale_fft[ij] * mask[ij];
      const float* src = fcbase + it * G_DIM;
      uint32_t wb[16];
      #pragma unroll
      for (int q = 0; q < 8; ++q) {
        float4 v = ((const float4*)src)[q];
        wb[2*q]   = pack2bf16(v.x * sf, v.y * sf);
        wb[2*q+1] = pack2bf16(v.z * sf, v.w * sf);
      }
      ((uint4*)Brow)[0] = make_uint4(wb[0],  wb[1],  wb[2],  wb[3]);
      ((uint4*)Brow)[1] = make_uint4(wb[4],  wb[5],  wb[6],  wb[7]);
      ((uint4*)Brow)[2] = make_uint4(wb[8],  wb[9],  wb[10], wb[11]);
      ((uint4*)Brow)[3] = make_uint4(wb[12], wb[13], wb[14], wb[15]);
    }
    __syncthreads();
    #pragma unroll
    for (int ks = 0; ks < 2; ++ks) {
      s8v a[4], b[4];
      #pragma unroll
      for (int tm = 0; tm < 4; ++tm)
        a[tm] = *(const s8v*)&A_lds[(wm * 64 + tm * 16 + l15) * PITCH + ks * 32 + kgrp];
      #pragma unroll
      for (int tn = 0; tn < 4; ++tn)
        b[tn] = *(const s8v*)&B_lds[(wn * 64 + tn * 16 + l15) * PITCH + ks * 32 + kgrp];
      #pragma unroll
      for (int tm = 0; tm < 4; ++tm)
        #pragma unroll
        for (int tn = 0; tn < 4; ++tn)
          acc[tm][tn] = __builtin_amdgcn_mfma_f32_16x16x32_bf16(a[tm], b[tn], acc[tm][tn], 0, 0, 0);
    }
  }

  __syncthreads();
  {
    const float* xb = xrow + half * 8;
    float4 v0 = ((const float4*)xb)[0];
    float4 v1 = ((const float4*)xb)[1];
    uint32_t a0 = pack2bf16(silu_f(v0.x), silu_f(v0.y));
    uint32_t a1 = pack2bf16(silu_f(v0.z), silu_f(v0.w));
    uint32_t a2 = pack2bf16(silu_f(v1.x), silu_f(v1.y));
    uint32_t a3 = pack2bf16(silu_f(v1.z), silu_f(v1.w));
    ((uint4*)&A_lds[row * PITCH + half * 8])[0]      = make_uint4(a0, a1, a2, a3);
    ((uint4*)&A_lds[row * PITCH + 16 + half * 8])[0] = make_uint4(0, 0, 0, 0);
    uint32_t w[4];
    #pragma unroll
    for (int p = 0; p < 4; ++p) {
      const int ia = i0 + half * 8 + 2 * p;
      const size_t o0 = (size_t)ia * O_DIM + jg;
      const size_t o1 = o0 + O_DIM;
      w[p] = pack2bf16(scale_base[o0] * mask[o0], scale_base[o1] * mask[o1]);
    }
    ((uint4*)&B_lds[row * PITCH + half * 8])[0]      = make_uint4(w[0], w[1], w[2], w[3]);
    ((uint4*)&B_lds[row * PITCH + 16 + half * 8])[0] = make_uint4(0, 0, 0, 0);
  }
  __syncthreads();
  {
    s8v a[4], b[4];
    #pragma unroll
    for (int tm = 0; tm < 4; ++tm)
      a[tm] = *(const s8v*)&A_lds[(wm * 64 + tm * 16 + l15) * PITCH + kgrp];
    #pragma unroll
    for (int tn = 0; tn < 4; ++tn)
      b[tn] = *(const s8v*)&B_lds[(wn * 64 + tn * 16 + l15) * PITCH + kgrp];
    #pragma unroll
    for (int tm = 0; tm < 4; ++tm)
      #pragma unroll
      for (int tn = 0; tn < 4; ++tn)
        acc[tm][tn] = __builtin_amdgcn_mfma_f32_16x16x32_bf16(a[tm], b[tn], acc[tm][tn], 0, 0, 0);
  }

  const int quad = lane >> 4;
  #pragma unroll
  for (int tm = 0; tm < 4; ++tm) {
    #pragma unroll
    for (int tn = 0; tn < 4; ++tn) {
      const int n_g = bn * BN + wn * 64 + tn * 16 + l15;
      f4v v = acc[tm][tn];
      #pragma unroll
      for (int r = 0; r < 4; ++r) {
        const int m_g = bm * BM + wm * 64 + tm * 16 + quad * 4 + r;
        float val = v[r];
        if (kc == 0) val += bias[n_g];
        atomicAdd(&out[(size_t)m_g * O_DIM + n_g], val);
      }
    }
  }
}

extern "C" void kernel_launch(void* const* d_in, const int* in_sizes, int n_in,
                              void* d_out, int out_size, void* d_ws, size_t ws_size,
                              hipStream_t stream) {
  const float* x          = (const float*)d_in[0];
  const float* fc         = (const float*)d_in[1];
  const float* bias       = (const float*)d_in[2];
  const float* mask       = (const float*)d_in[3];
  const float* scale_base = (const float*)d_in[4];
  const float* scale_fft  = (const float*)d_in[5];
  float* out = (float*)d_out;

  const size_t BP_B   = (size_t)I_DIM * O_DIM * 64 * 2;        //  8,388,608
  const size_t PART_B = (size_t)KSPLIT * B_DIM * O_DIM * 4;    // 67,108,864

  if (ws_size >= BP_B + PART_B) {
    short* Bp      = (short*)d_ws;
    float* partial = (float*)((char*)d_ws + BP_B);
    prep_bs_kernel<<<dim3(256), dim3(256), 0, stream>>>(fc, mask, scale_fft, Bp);
    kan_main2<<<dim3(1024), dim3(256), 0, stream>>>(x, Bp, mask, scale_base, partial);
    reduce_kernel<<<dim3(1024), dim3(256), 0, stream>>>(partial, bias, out, KSPLIT);
  } else {
    hipMemsetAsync(d_out, 0, (size_t)out_size * sizeof(float), stream);
    kan_fft_fallback<<<dim3(1024), dim3(256), 0, stream>>>(
        x, fc, bias, mask, scale_base, scale_fft, out);
  }
}